// Round 11
// baseline (218.567 us; speedup 1.0000x reference)
//
#include <hip/hip_runtime.h>
#include <hip/hip_cooperative_groups.h>
#include <math.h>

namespace cg = cooperative_groups;

#define NHID 128
#define TILE_E 128
#define LDK 264   // padded K stride in bf16 elems (fallback kernel)
#define TILE_R 32 // phase-1 rows per block-iteration
#define LDA 136   // sA row stride in ushorts: 272 B = 17 x 16 B chunks

typedef __bf16 bf16x8 __attribute__((ext_vector_type(8)));
typedef float f32x4 __attribute__((ext_vector_type(4)));
typedef float f32x2 __attribute__((ext_vector_type(2)));
typedef unsigned short u16x8 __attribute__((ext_vector_type(8)));

__device__ __forceinline__ unsigned short f2bf(float f) {
  unsigned int u = __float_as_uint(f);
  u += 0x7fffu + ((u >> 16) & 1u);   // RNE
  return (unsigned short)(u >> 16);
}
__device__ __forceinline__ float bf2f(unsigned short u) {
  return __uint_as_float(((unsigned int)u) << 16);
}

// ============================================================================
// PHASE 1 BODY (r10-proven): 32-row tiles through double-buffered bf16 LDS,
// one barrier/tile, prefetch-before-barrier, fp8-e4m3 output (8 B/lane).
// Shared between the fused cooperative kernel and the standalone fallback.
// ============================================================================
template <typename SA, typename SCC>
__device__ __forceinline__
void phase1_body(SA& sA, SCC& sC,
                 const float* __restrict__ inputs,
                 const float* __restrict__ W1,
                 const float* __restrict__ bias1,
                 unsigned char* __restrict__ AB8,
                 int n_nodes, int grid_sz, int bid, int tid)
{
  const int lane = tid & 63;
  const int w    = tid >> 6;          // wave 0..3 -> output cols w*64..+63
  const int m15  = lane & 15;
  const int quad = lane >> 4;
  const int koff = (w >> 1) * NHID;   // W1 row offset: 0 (A half) or 128 (B half)
  const int cW   = (w & 1) * 64;      // W1 col base within half

  // ---- W1 B-fragments in registers: bw[ks][nt], loop-invariant (64 VGPR) ----
  bf16x8 bw[4][4];
  #pragma unroll
  for (int ks = 0; ks < 4; ++ks) {
    #pragma unroll
    for (int nt = 0; nt < 4; ++nt) {
      u16x8 t;
      #pragma unroll
      for (int j = 0; j < 8; ++j)
        t[j] = f2bf(W1[(size_t)(koff + ks * 32 + quad * 8 + j) * NHID + cW + nt * 16 + m15]);
      bw[ks][nt] = __builtin_bit_cast(bf16x8, t);
    }
  }

  float bias[4];
  #pragma unroll
  for (int nt = 0; nt < 4; ++nt)
    bias[nt] = (w < 2) ? bias1[cW + nt * 16 + m15] : 0.f;

  const int srow = tid >> 3;          // staging: thread covers 64 B of row srow
  const int scol = (tid & 7) * 16;

  const int ntiles = (n_nodes + TILE_R - 1) / TILE_R;
  int t = bid;

  float4 st0, st1, st2, st3;
  if (t < ntiles) {
    int r = t * TILE_R + srow;
    if (r >= n_nodes) r = n_nodes - 1;
    const float* p = inputs + (size_t)r * NHID + scol;
    st0 = *(const float4*)(p);
    st1 = *(const float4*)(p + 4);
    st2 = *(const float4*)(p + 8);
    st3 = *(const float4*)(p + 12);
  }

  int cur = 0;
  for (; t < ntiles; t += grid_sz) {
    // stage_write: fp32 regs -> bf16 LDS tile
    {
      u16x8 w0, w1;
      w0[0] = f2bf(st0.x); w0[1] = f2bf(st0.y); w0[2] = f2bf(st0.z); w0[3] = f2bf(st0.w);
      w0[4] = f2bf(st1.x); w0[5] = f2bf(st1.y); w0[6] = f2bf(st1.z); w0[7] = f2bf(st1.w);
      w1[0] = f2bf(st2.x); w1[1] = f2bf(st2.y); w1[2] = f2bf(st2.z); w1[3] = f2bf(st2.w);
      w1[4] = f2bf(st3.x); w1[5] = f2bf(st3.y); w1[6] = f2bf(st3.z); w1[7] = f2bf(st3.w);
      *(u16x8*)&sA[cur][srow][scol]     = w0;
      *(u16x8*)&sA[cur][srow][scol + 8] = w1;
    }

    // issue next tile's loads; they fly across barrier + MFMA + epilogue
    {
      int tn = t + grid_sz;
      if (tn < ntiles) {
        int r = tn * TILE_R + srow;
        if (r >= n_nodes) r = n_nodes - 1;
        const float* p = inputs + (size_t)r * NHID + scol;
        st0 = *(const float4*)(p);
        st1 = *(const float4*)(p + 4);
        st2 = *(const float4*)(p + 8);
        st3 = *(const float4*)(p + 12);
      }
    }

    __syncthreads();

    const int rowbase = t * TILE_R;
    #pragma unroll
    for (int mt = 0; mt < 2; ++mt) {
      bf16x8 af[4];
      #pragma unroll
      for (int ks = 0; ks < 4; ++ks)
        af[ks] = __builtin_bit_cast(bf16x8,
                   *(const u16x8*)(&sA[cur][mt * 16 + m15][ks * 32 + quad * 8]));

      f32x4 acc[4];
      #pragma unroll
      for (int nt = 0; nt < 4; ++nt)
        acc[nt] = (f32x4){0.f, 0.f, 0.f, 0.f};

      #pragma unroll
      for (int ks = 0; ks < 4; ++ks)
        #pragma unroll
        for (int nt = 0; nt < 4; ++nt)
          acc[nt] = __builtin_amdgcn_mfma_f32_16x16x32_bf16(af[ks], bw[ks][nt], acc[nt], 0, 0, 0);

      #pragma unroll
      for (int nt = 0; nt < 4; ++nt)
        #pragma unroll
        for (int r = 0; r < 4; ++r)
          sC[w][quad * 4 + r][nt * 16 + m15] = f2bf(acc[nt][r] + bias[nt]);

      // store stage: bf16 row-slices -> fp8-e4m3, 8 B/lane coalesced
      #pragma unroll
      for (int p = 0; p < 2; ++p) {
        const int row  = p * 8 + (lane >> 3);
        const int node = rowbase + mt * 16 + row;
        if (node < n_nodes) {
          u16x8 v = *(const u16x8*)&sC[w][row][(lane & 7) * 8];
          float a0 = bf2f((unsigned short)v[0]), a1 = bf2f((unsigned short)v[1]);
          float a2 = bf2f((unsigned short)v[2]), a3 = bf2f((unsigned short)v[3]);
          float a4 = bf2f((unsigned short)v[4]), a5 = bf2f((unsigned short)v[5]);
          float a6 = bf2f((unsigned short)v[6]), a7 = bf2f((unsigned short)v[7]);
          unsigned int w0 = __builtin_amdgcn_cvt_pk_fp8_f32(a0, a1, 0, false);
          w0 = __builtin_amdgcn_cvt_pk_fp8_f32(a2, a3, w0, true);
          unsigned int w1 = __builtin_amdgcn_cvt_pk_fp8_f32(a4, a5, 0, false);
          w1 = __builtin_amdgcn_cvt_pk_fp8_f32(a6, a7, w1, true);
          uint2 st; st.x = w0; st.y = w1;
          *(uint2*)(AB8 + (size_t)node * 256 + w * 64 + (lane & 7) * 8) = st;
        }
      }
    }
    cur ^= 1;
  }
}

// ============================================================================
// PHASE 2 BODY (r10-proven): fp8 gathers, 16 lanes/edge, 4-edge flat unroll.
// ============================================================================
__device__ __forceinline__
void phase2_body(const unsigned char* __restrict__ AB8,
                 const int* __restrict__ x_idx,
                 const int* __restrict__ y_idx,
                 const float* __restrict__ W2,
                 const float* __restrict__ bias2,
                 float* __restrict__ out,
                 int n_edges, int grid_sz, int bid, int tid)
{
  const int g = tid >> 4;   // group 0..15 within block
  const int l = tid & 15;   // lane within group; owns channels l*8..l*8+7

  float w2[8];
  {
    float4 a = *(const float4*)(W2 + l * 8);
    float4 b = *(const float4*)(W2 + l * 8 + 4);
    w2[0] = a.x; w2[1] = a.y; w2[2] = a.z; w2[3] = a.w;
    w2[4] = b.x; w2[5] = b.y; w2[6] = b.z; w2[7] = b.w;
  }
  const float b2   = bias2[0];
  const int   last = n_edges - 1;
  const int   step = grid_sz * 64;

  for (int base = bid * 64; base < n_edges; base += step) {
    int e[4], xi[4], yi[4];
    #pragma unroll
    for (int k = 0; k < 4; ++k) {
      e[k] = base + 16 * k + g;
      int c = e[k] < last ? e[k] : last;
      xi[k] = x_idx[c];
      yi[k] = y_idx[c];
    }

    uint2 ax[4], by[4];
    #pragma unroll
    for (int k = 0; k < 4; ++k) {
      ax[k] = *(const uint2*)(AB8 + (size_t)xi[k] * 256 + l * 8);
      by[k] = *(const uint2*)(AB8 + (size_t)yi[k] * 256 + 128 + l * 8);
    }

    float s[4] = {0.f, 0.f, 0.f, 0.f};
    #pragma unroll
    for (int k = 0; k < 4; ++k) {
      f32x2 a0 = __builtin_amdgcn_cvt_pk_f32_fp8(ax[k].x, false);
      f32x2 a1 = __builtin_amdgcn_cvt_pk_f32_fp8(ax[k].x, true);
      f32x2 a2 = __builtin_amdgcn_cvt_pk_f32_fp8(ax[k].y, false);
      f32x2 a3 = __builtin_amdgcn_cvt_pk_f32_fp8(ax[k].y, true);
      f32x2 b0 = __builtin_amdgcn_cvt_pk_f32_fp8(by[k].x, false);
      f32x2 b1 = __builtin_amdgcn_cvt_pk_f32_fp8(by[k].x, true);
      f32x2 b2v = __builtin_amdgcn_cvt_pk_f32_fp8(by[k].y, false);
      f32x2 b3 = __builtin_amdgcn_cvt_pk_f32_fp8(by[k].y, true);
      float h;
      h = fmaxf(a0.x + b0.x, 0.f);  s[k] = fmaf(h, w2[0], s[k]);
      h = fmaxf(a0.y + b0.y, 0.f);  s[k] = fmaf(h, w2[1], s[k]);
      h = fmaxf(a1.x + b1.x, 0.f);  s[k] = fmaf(h, w2[2], s[k]);
      h = fmaxf(a1.y + b1.y, 0.f);  s[k] = fmaf(h, w2[3], s[k]);
      h = fmaxf(a2.x + b2v.x, 0.f); s[k] = fmaf(h, w2[4], s[k]);
      h = fmaxf(a2.y + b2v.y, 0.f); s[k] = fmaf(h, w2[5], s[k]);
      h = fmaxf(a3.x + b3.x, 0.f);  s[k] = fmaf(h, w2[6], s[k]);
      h = fmaxf(a3.y + b3.y, 0.f);  s[k] = fmaf(h, w2[7], s[k]);
    }
    #pragma unroll
    for (int d = 1; d < 16; d <<= 1) {
      #pragma unroll
      for (int k = 0; k < 4; ++k)
        s[k] += __shfl_xor(s[k], d);
    }
    if (l == 0) {
      #pragma unroll
      for (int k = 0; k < 4; ++k)
        if (e[k] < n_edges)
          out[e[k]] = 1.f / (1.f + __expf(-(s[k] + b2)));
    }
  }
}

// ============================================================================
// Fused cooperative kernel. min_waves=2 -> VGPR cap 128 (r8's failure was
// min_waves=5 -> 48 VGPR -> spills). Grid = 2 blocks/CU x 256, guaranteed
// co-resident; grid.sync() replaces the p1->p2 dispatch gap; p1 amortizes
// its W-fragment prologue over ~6 tiles/block.
// ============================================================================
__global__ __launch_bounds__(256, 2)
void fused_decoder(const float* __restrict__ inputs,
                   const int* __restrict__ x_idx,
                   const int* __restrict__ y_idx,
                   const float* __restrict__ W1,
                   const float* __restrict__ bias1,
                   const float* __restrict__ W2,
                   const float* __restrict__ bias2,
                   unsigned char* __restrict__ AB8,
                   float* __restrict__ out,
                   int n_nodes, int n_edges)
{
  __shared__ __align__(16) unsigned short sA[2][TILE_R][LDA]; // 17.4 KB
  __shared__ __align__(16) unsigned short sC[4][16][72];      // 9.2 KB

  phase1_body(sA, sC, inputs, W1, bias1, AB8, n_nodes,
              gridDim.x, blockIdx.x, threadIdx.x);

  cg::this_grid().sync();

  phase2_body(AB8, x_idx, y_idx, W2, bias2, out, n_edges,
              gridDim.x, blockIdx.x, threadIdx.x);
}

// ============================================================================
// Standalone two-dispatch path (r10-proven; used if coop launch unavailable)
// ============================================================================
__global__ __launch_bounds__(256)
void precompute_ab(const float* __restrict__ inputs,
                   const float* __restrict__ W1,
                   const float* __restrict__ bias1,
                   unsigned char* __restrict__ AB8,
                   int n_nodes)
{
  __shared__ __align__(16) unsigned short sA[2][TILE_R][LDA];
  __shared__ __align__(16) unsigned short sC[4][16][72];
  phase1_body(sA, sC, inputs, W1, bias1, AB8, n_nodes,
              gridDim.x, blockIdx.x, threadIdx.x);
}

__global__ __launch_bounds__(256, 4)
void edge_eval(const unsigned char* __restrict__ AB8,
               const int* __restrict__ x_idx,
               const int* __restrict__ y_idx,
               const float* __restrict__ W2,
               const float* __restrict__ bias2,
               float* __restrict__ out,
               int n_edges)
{
  phase2_body(AB8, x_idx, y_idx, W2, bias2, out, n_edges,
              gridDim.x, blockIdx.x, threadIdx.x);
}

// ============================================================================
// Fallback: fused bf16 kernel (used only if workspace is too small)
// ============================================================================
__global__ __launch_bounds__(256, 1)
void mlp_edge_decoder(const float* __restrict__ inputs,
                      const int* __restrict__ x_idx,
                      const int* __restrict__ y_idx,
                      const float* __restrict__ W1,
                      const float* __restrict__ bias1,
                      const float* __restrict__ W2,
                      const float* __restrict__ bias2,
                      float* __restrict__ out,
                      int n_edges)
{
  __shared__ __align__(16) unsigned short sW1T[NHID][LDK];
  __shared__ __align__(16) unsigned short sAx[TILE_E][LDK];
  __shared__ float sB1[NHID];
  __shared__ float sW2[NHID];
  __shared__ float sRed[2][TILE_E];

  const int tid  = threadIdx.x;
  const int lane = tid & 63;
  const int wv   = tid >> 6;
  const int seg  = tid & 63;
  const int m15  = lane & 15;
  const int quad = lane >> 4;
  const int eh   = wv >> 1;
  const int ch   = wv & 1;

  for (int i = tid; i < 256 * NHID; i += 256) {
    int k = i >> 7;
    int n = i & 127;
    sW1T[n][k] = f2bf(W1[i]);
  }
  if (tid < NHID) { sB1[tid] = bias1[tid]; sW2[tid] = W2[tid]; }
  const float b2 = bias2[0];

  const int stride = gridDim.x * TILE_E;
  int ebase = blockIdx.x * TILE_E;

  float4 stage[32];
  #pragma unroll
  for (int j = 0; j < 32; ++j) {
    int e  = ebase + 4 * j + wv;
    int ec = (e < n_edges) ? e : 0;
    int idx = (seg < 32) ? x_idx[ec] : y_idx[ec];
    stage[j] = *(const float4*)(inputs + (size_t)idx * NHID + (seg & 31) * 4);
  }

  for (; ebase < n_edges; ebase += stride) {
    #pragma unroll
    for (int j = 0; j < 32; ++j) {
      int r = wv + 4 * j;
      ushort4 p;
      p.x = f2bf(stage[j].x);
      p.y = f2bf(stage[j].y);
      p.z = f2bf(stage[j].z);
      p.w = f2bf(stage[j].w);
      *(ushort4*)(&sAx[r][seg * 4]) = p;
    }
    __syncthreads();

    {
      int nb = ebase + stride;
      if (nb < n_edges) {
        #pragma unroll
        for (int j = 0; j < 32; ++j) {
          int e  = nb + 4 * j + wv;
          int ec = (e < n_edges) ? e : 0;
          int idx = (seg < 32) ? x_idx[ec] : y_idx[ec];
          stage[j] = *(const float4*)(inputs + (size_t)idx * NHID + (seg & 31) * 4);
        }
      }
    }

    f32x4 acc[4][4];
    #pragma unroll
    for (int mt = 0; mt < 4; ++mt)
      #pragma unroll
      for (int nt = 0; nt < 4; ++nt)
        acc[mt][nt] = (f32x4){0.f, 0.f, 0.f, 0.f};

    #pragma unroll
    for (int ks = 0; ks < 8; ++ks) {
      bf16x8 af[4], bfr[4];
      #pragma unroll
      for (int mt = 0; mt < 4; ++mt)
        af[mt] = __builtin_bit_cast(bf16x8,
                   *(const u16x8*)(&sAx[eh * 64 + mt * 16 + m15][ks * 32 + quad * 8]));
      #pragma unroll
      for (int nt = 0; nt < 4; ++nt)
        bfr[nt] = __builtin_bit_cast(bf16x8,
                   *(const u16x8*)(&sW1T[ch * 64 + nt * 16 + m15][ks * 32 + quad * 8]));
      #pragma unroll
      for (int mt = 0; mt < 4; ++mt)
        #pragma unroll
        for (int nt = 0; nt < 4; ++nt)
          acc[mt][nt] = __builtin_amdgcn_mfma_f32_16x16x32_bf16(af[mt], bfr[nt], acc[mt][nt], 0, 0, 0);
    }

    #pragma unroll
    for (int mt = 0; mt < 4; ++mt) {
      #pragma unroll
      for (int r = 0; r < 4; ++r) {
        float s = 0.f;
        #pragma unroll
        for (int nt = 0; nt < 4; ++nt) {
          int c = ch * 64 + nt * 16 + m15;
          float h = acc[mt][nt][r] + sB1[c];
          h = fmaxf(h, 0.f);
          s = fmaf(h, sW2[c], s);
        }
        s += __shfl_xor(s, 1);
        s += __shfl_xor(s, 2);
        s += __shfl_xor(s, 4);
        s += __shfl_xor(s, 8);
        if (m15 == 0) sRed[ch][eh * 64 + mt * 16 + quad * 4 + r] = s;
      }
    }
    __syncthreads();

    if (tid < TILE_E) {
      int e = ebase + tid;
      if (e < n_edges) {
        float s = sRed[0][tid] + sRed[1][tid] + b2;
        out[e] = 1.f / (1.f + __expf(-s));
      }
    }
  }
}

extern "C" void kernel_launch(void* const* d_in, const int* in_sizes, int n_in,
                              void* d_out, int out_size, void* d_ws, size_t ws_size,
                              hipStream_t stream) {
  const float* inputs = (const float*)d_in[0];
  const int*   x_idx  = (const int*)d_in[1];
  const int*   y_idx  = (const int*)d_in[2];
  const float* W1     = (const float*)d_in[3];
  const float* bias1  = (const float*)d_in[4];
  const float* W2     = (const float*)d_in[5];
  const float* bias2  = (const float*)d_in[6];
  float* out = (float*)d_out;
  int n_edges = in_sizes[1];
  int n_nodes = in_sizes[0] / NHID;

  const size_t need = (size_t)n_nodes * 256;   // fp8: 256 B/node
  if (d_ws != nullptr && ws_size >= need) {
    unsigned char* AB8 = (unsigned char*)d_ws;

    int nb = 0;
    hipError_t oe = hipOccupancyMaxActiveBlocksPerMultiprocessor(
                        &nb, fused_decoder, 256, 0);
    bool coop_ok = (oe == hipSuccess && nb >= 1);
    if (coop_ok) {
      if (nb > 2) nb = 2;                     // min_waves=2 contract: <=2/CU
      int grid = nb * 256;
      void* args[] = {&inputs, &x_idx, &y_idx, &W1, &bias1, &W2, &bias2,
                      &AB8, &out, &n_nodes, &n_edges};
      hipError_t le = hipLaunchCooperativeKernel((void*)fused_decoder,
                                                 dim3(grid), dim3(256),
                                                 args, 0, stream);
      if (le == hipSuccess) return;
    }

    // fallback: proven r10 two-dispatch path
    const int ntiles = (n_nodes + TILE_R - 1) / TILE_R;
    int grid1 = (ntiles + 2) / 3;
    if (grid1 < 1) grid1 = 1;
    hipLaunchKernelGGL(precompute_ab, dim3(grid1), dim3(256), 0, stream,
                       inputs, W1, bias1, AB8, n_nodes);
    hipLaunchKernelGGL(edge_eval, dim3(2048), dim3(256), 0, stream,
                       AB8, x_idx, y_idx, W2, bias2, out, n_edges);
  } else {
    hipLaunchKernelGGL(mlp_edge_decoder, dim3(512), dim3(256), 0, stream,
                       inputs, x_idx, y_idx, W1, bias1, W2, bias2, out, n_edges);
  }
}

// Round 12
// 131.789 us; speedup vs baseline: 1.6585x; 1.6585x over previous
//
#include <hip/hip_runtime.h>
#include <math.h>

#define NHID 128
#define TILE_E 128
#define LDK 264   // padded K stride in bf16 elems (fallback kernel)
#define TILE_R 32 // phase-1 rows per block-iteration
#define LDA 136   // sA row stride in ushorts: 272 B = 17 x 16 B chunks

typedef __bf16 bf16x8 __attribute__((ext_vector_type(8)));
typedef float f32x4 __attribute__((ext_vector_type(4)));
typedef float f32x2 __attribute__((ext_vector_type(2)));
typedef unsigned short u16x8 __attribute__((ext_vector_type(8)));

__device__ __forceinline__ unsigned short f2bf(float f) {
  unsigned int u = __float_as_uint(f);
  u += 0x7fffu + ((u >> 16) & 1u);   // RNE
  return (unsigned short)(u >> 16);
}
__device__ __forceinline__ float bf2f(unsigned short u) {
  return __uint_as_float(((unsigned int)u) << 16);
}

// ============================================================================
// Phase 1 (r10 measured-best, 132.7us total): AB8[node][0:128] =
// fp8(inputs·W1_A + bias1), AB8[node][128:256] = fp8(inputs·W1_B).
// 32-row tiles through double-buffered bf16 LDS; one barrier/tile;
// prefetch-before-barrier; fp8-e4m3 stores (8 B/lane, half the write bytes).
// ============================================================================
__global__ __launch_bounds__(256)
void precompute_ab(const float* __restrict__ inputs,
                   const float* __restrict__ W1,
                   const float* __restrict__ bias1,
                   unsigned char* __restrict__ AB8,
                   int n_nodes)
{
  __shared__ __align__(16) unsigned short sA[2][TILE_R][LDA]; // 17.4 KB
  __shared__ __align__(16) unsigned short sC[4][16][72];      // 9.2 KB, wave-private repack

  const int tid  = threadIdx.x;
  const int lane = tid & 63;
  const int w    = tid >> 6;          // wave 0..3 -> output cols w*64..+63
  const int m15  = lane & 15;
  const int quad = lane >> 4;
  const int koff = (w >> 1) * NHID;   // W1 row offset: 0 (A half) or 128 (B half)
  const int cW   = (w & 1) * 64;      // W1 col base within half

  // ---- W1 B-fragments in registers: bw[ks][nt], loop-invariant ----
  bf16x8 bw[4][4];
  #pragma unroll
  for (int ks = 0; ks < 4; ++ks) {
    #pragma unroll
    for (int nt = 0; nt < 4; ++nt) {
      u16x8 t;
      #pragma unroll
      for (int j = 0; j < 8; ++j)
        t[j] = f2bf(W1[(size_t)(koff + ks * 32 + quad * 8 + j) * NHID + cW + nt * 16 + m15]);
      bw[ks][nt] = __builtin_bit_cast(bf16x8, t);
    }
  }

  // bias1 folded into the A half only (waves 0,1)
  float bias[4];
  #pragma unroll
  for (int nt = 0; nt < 4; ++nt)
    bias[nt] = (w < 2) ? bias1[cW + nt * 16 + m15] : 0.f;

  // staging map: thread t covers 16 floats (64 B) of row t>>3
  const int srow = tid >> 3;          // 0..31
  const int scol = (tid & 7) * 16;    // logical col (floats == bf16 elems)

  const int ntiles = (n_nodes + TILE_R - 1) / TILE_R;
  const int stride = gridDim.x;
  int t = blockIdx.x;

  // ---- prologue: load tile t slice into regs ----
  float4 st0, st1, st2, st3;
  {
    int r = t * TILE_R + srow;
    if (r >= n_nodes) r = n_nodes - 1;
    if (r < 0) r = 0;
    const float* p = inputs + (size_t)r * NHID + scol;
    st0 = *(const float4*)(p);
    st1 = *(const float4*)(p + 4);
    st2 = *(const float4*)(p + 8);
    st3 = *(const float4*)(p + 12);
  }

  int cur = 0;
  for (; t < ntiles; t += stride) {
    // ---- stage_write: convert staged regs -> bf16 LDS tile ----
    {
      u16x8 w0, w1;
      w0[0] = f2bf(st0.x); w0[1] = f2bf(st0.y); w0[2] = f2bf(st0.z); w0[3] = f2bf(st0.w);
      w0[4] = f2bf(st1.x); w0[5] = f2bf(st1.y); w0[6] = f2bf(st1.z); w0[7] = f2bf(st1.w);
      w1[0] = f2bf(st2.x); w1[1] = f2bf(st2.y); w1[2] = f2bf(st2.z); w1[3] = f2bf(st2.w);
      w1[4] = f2bf(st3.x); w1[5] = f2bf(st3.y); w1[6] = f2bf(st3.z); w1[7] = f2bf(st3.w);
      *(u16x8*)&sA[cur][srow][scol]     = w0;
      *(u16x8*)&sA[cur][srow][scol + 8] = w1;
    }

    // ---- issue next tile's loads; they fly across barrier + MFMA + epilogue ----
    {
      int tn = t + stride;
      if (tn < ntiles) {
        int r = tn * TILE_R + srow;
        if (r >= n_nodes) r = n_nodes - 1;
        const float* p = inputs + (size_t)r * NHID + scol;
        st0 = *(const float4*)(p);
        st1 = *(const float4*)(p + 4);
        st2 = *(const float4*)(p + 8);
        st3 = *(const float4*)(p + 12);
      }
    }

    __syncthreads();   // sA[cur] visible; writes next iter go to sA[cur^1] (disjoint)

    const int rowbase = t * TILE_R;
    #pragma unroll
    for (int mt = 0; mt < 2; ++mt) {
      bf16x8 af[4];
      #pragma unroll
      for (int ks = 0; ks < 4; ++ks)
        af[ks] = __builtin_bit_cast(bf16x8,
                   *(const u16x8*)(&sA[cur][mt * 16 + m15][ks * 32 + quad * 8]));

      f32x4 acc[4];
      #pragma unroll
      for (int nt = 0; nt < 4; ++nt)
        acc[nt] = (f32x4){0.f, 0.f, 0.f, 0.f};

      #pragma unroll
      for (int ks = 0; ks < 4; ++ks)
        #pragma unroll
        for (int nt = 0; nt < 4; ++nt)
          acc[nt] = __builtin_amdgcn_mfma_f32_16x16x32_bf16(af[ks], bw[ks][nt], acc[nt], 0, 0, 0);

      // epilogue: +bias, cvt bf16, wave-private LDS repack
      #pragma unroll
      for (int nt = 0; nt < 4; ++nt)
        #pragma unroll
        for (int r = 0; r < 4; ++r)
          sC[w][quad * 4 + r][nt * 16 + m15] = f2bf(acc[nt][r] + bias[nt]);

      // store stage: bf16 row-slices -> fp8-e4m3, 8 B/lane coalesced
      #pragma unroll
      for (int p = 0; p < 2; ++p) {
        const int row  = p * 8 + (lane >> 3);
        const int node = rowbase + mt * 16 + row;
        if (node < n_nodes) {
          u16x8 v = *(const u16x8*)&sC[w][row][(lane & 7) * 8];
          float a0 = bf2f((unsigned short)v[0]), a1 = bf2f((unsigned short)v[1]);
          float a2 = bf2f((unsigned short)v[2]), a3 = bf2f((unsigned short)v[3]);
          float a4 = bf2f((unsigned short)v[4]), a5 = bf2f((unsigned short)v[5]);
          float a6 = bf2f((unsigned short)v[6]), a7 = bf2f((unsigned short)v[7]);
          unsigned int w0 = __builtin_amdgcn_cvt_pk_fp8_f32(a0, a1, 0, false);
          w0 = __builtin_amdgcn_cvt_pk_fp8_f32(a2, a3, w0, true);
          unsigned int w1 = __builtin_amdgcn_cvt_pk_fp8_f32(a4, a5, 0, false);
          w1 = __builtin_amdgcn_cvt_pk_fp8_f32(a6, a7, w1, true);
          uint2 st; st.x = w0; st.y = w1;
          *(uint2*)(AB8 + (size_t)node * 256 + w * 64 + (lane & 7) * 8) = st;
        }
      }
    }
    cur ^= 1;
  }
}

// ============================================================================
// Phase 2 (r10 measured-best): out[e] = sigmoid( relu(A8[x]+B8[y]) · W2 + b2 ).
// fp8 gathers: 16 lanes/edge, uint2 (8 B = 8 channels)/lane, 4-edge flat
// unroll (8 gathers/lane in flight), zero LDS -> 32 waves/CU latency cover.
// ============================================================================
__global__ __launch_bounds__(256, 4)
void edge_eval(const unsigned char* __restrict__ AB8,
               const int* __restrict__ x_idx,
               const int* __restrict__ y_idx,
               const float* __restrict__ W2,
               const float* __restrict__ bias2,
               float* __restrict__ out,
               int n_edges)
{
  const int tid = threadIdx.x;
  const int g   = tid >> 4;   // group 0..15 within block
  const int l   = tid & 15;   // lane within group; owns channels l*8..l*8+7

  float w2[8];
  {
    float4 a = *(const float4*)(W2 + l * 8);
    float4 b = *(const float4*)(W2 + l * 8 + 4);
    w2[0] = a.x; w2[1] = a.y; w2[2] = a.z; w2[3] = a.w;
    w2[4] = b.x; w2[5] = b.y; w2[6] = b.z; w2[7] = b.w;
  }
  const float b2   = bias2[0];
  const int   last = n_edges - 1;
  const int   step = gridDim.x * 64;

  for (int base = blockIdx.x * 64; base < n_edges; base += step) {
    int e[4], xi[4], yi[4];
    #pragma unroll
    for (int k = 0; k < 4; ++k) {
      e[k] = base + 16 * k + g;
      int c = e[k] < last ? e[k] : last;
      xi[k] = x_idx[c];
      yi[k] = y_idx[c];
    }

    uint2 ax[4], by[4];
    #pragma unroll
    for (int k = 0; k < 4; ++k) {
      ax[k] = *(const uint2*)(AB8 + (size_t)xi[k] * 256 + l * 8);
      by[k] = *(const uint2*)(AB8 + (size_t)yi[k] * 256 + 128 + l * 8);
    }

    float s[4] = {0.f, 0.f, 0.f, 0.f};
    #pragma unroll
    for (int k = 0; k < 4; ++k) {
      f32x2 a0 = __builtin_amdgcn_cvt_pk_f32_fp8(ax[k].x, false);  // ch +0,+1
      f32x2 a1 = __builtin_amdgcn_cvt_pk_f32_fp8(ax[k].x, true);   // ch +2,+3
      f32x2 a2 = __builtin_amdgcn_cvt_pk_f32_fp8(ax[k].y, false);  // ch +4,+5
      f32x2 a3 = __builtin_amdgcn_cvt_pk_f32_fp8(ax[k].y, true);   // ch +6,+7
      f32x2 b0 = __builtin_amdgcn_cvt_pk_f32_fp8(by[k].x, false);
      f32x2 b1 = __builtin_amdgcn_cvt_pk_f32_fp8(by[k].x, true);
      f32x2 b2v = __builtin_amdgcn_cvt_pk_f32_fp8(by[k].y, false);
      f32x2 b3 = __builtin_amdgcn_cvt_pk_f32_fp8(by[k].y, true);
      float h;
      h = fmaxf(a0.x + b0.x, 0.f);  s[k] = fmaf(h, w2[0], s[k]);
      h = fmaxf(a0.y + b0.y, 0.f);  s[k] = fmaf(h, w2[1], s[k]);
      h = fmaxf(a1.x + b1.x, 0.f);  s[k] = fmaf(h, w2[2], s[k]);
      h = fmaxf(a1.y + b1.y, 0.f);  s[k] = fmaf(h, w2[3], s[k]);
      h = fmaxf(a2.x + b2v.x, 0.f); s[k] = fmaf(h, w2[4], s[k]);
      h = fmaxf(a2.y + b2v.y, 0.f); s[k] = fmaf(h, w2[5], s[k]);
      h = fmaxf(a3.x + b3.x, 0.f);  s[k] = fmaf(h, w2[6], s[k]);
      h = fmaxf(a3.y + b3.y, 0.f);  s[k] = fmaf(h, w2[7], s[k]);
    }
    #pragma unroll
    for (int d = 1; d < 16; d <<= 1) {
      #pragma unroll
      for (int k = 0; k < 4; ++k)
        s[k] += __shfl_xor(s[k], d);
    }
    if (l == 0) {
      #pragma unroll
      for (int k = 0; k < 4; ++k)
        if (e[k] < n_edges)
          out[e[k]] = 1.f / (1.f + __expf(-(s[k] + b2)));
    }
  }
}

// ============================================================================
// Fallback: fused bf16 kernel (used only if workspace is too small)
// ============================================================================
__global__ __launch_bounds__(256, 1)
void mlp_edge_decoder(const float* __restrict__ inputs,
                      const int* __restrict__ x_idx,
                      const int* __restrict__ y_idx,
                      const float* __restrict__ W1,
                      const float* __restrict__ bias1,
                      const float* __restrict__ W2,
                      const float* __restrict__ bias2,
                      float* __restrict__ out,
                      int n_edges)
{
  __shared__ __align__(16) unsigned short sW1T[NHID][LDK];
  __shared__ __align__(16) unsigned short sAx[TILE_E][LDK];
  __shared__ float sB1[NHID];
  __shared__ float sW2[NHID];
  __shared__ float sRed[2][TILE_E];

  const int tid  = threadIdx.x;
  const int lane = tid & 63;
  const int wv   = tid >> 6;
  const int seg  = tid & 63;
  const int m15  = lane & 15;
  const int quad = lane >> 4;
  const int eh   = wv >> 1;
  const int ch   = wv & 1;

  for (int i = tid; i < 256 * NHID; i += 256) {
    int k = i >> 7;
    int n = i & 127;
    sW1T[n][k] = f2bf(W1[i]);
  }
  if (tid < NHID) { sB1[tid] = bias1[tid]; sW2[tid] = W2[tid]; }
  const float b2 = bias2[0];

  const int stride = gridDim.x * TILE_E;
  int ebase = blockIdx.x * TILE_E;

  float4 stage[32];
  #pragma unroll
  for (int j = 0; j < 32; ++j) {
    int e  = ebase + 4 * j + wv;
    int ec = (e < n_edges) ? e : 0;
    int idx = (seg < 32) ? x_idx[ec] : y_idx[ec];
    stage[j] = *(const float4*)(inputs + (size_t)idx * NHID + (seg & 31) * 4);
  }

  for (; ebase < n_edges; ebase += stride) {
    #pragma unroll
    for (int j = 0; j < 32; ++j) {
      int r = wv + 4 * j;
      ushort4 p;
      p.x = f2bf(stage[j].x);
      p.y = f2bf(stage[j].y);
      p.z = f2bf(stage[j].z);
      p.w = f2bf(stage[j].w);
      *(ushort4*)(&sAx[r][seg * 4]) = p;
    }
    __syncthreads();

    {
      int nb = ebase + stride;
      if (nb < n_edges) {
        #pragma unroll
        for (int j = 0; j < 32; ++j) {
          int e  = nb + 4 * j + wv;
          int ec = (e < n_edges) ? e : 0;
          int idx = (seg < 32) ? x_idx[ec] : y_idx[ec];
          stage[j] = *(const float4*)(inputs + (size_t)idx * NHID + (seg & 31) * 4);
        }
      }
    }

    f32x4 acc[4][4];
    #pragma unroll
    for (int mt = 0; mt < 4; ++mt)
      #pragma unroll
      for (int nt = 0; nt < 4; ++nt)
        acc[mt][nt] = (f32x4){0.f, 0.f, 0.f, 0.f};

    #pragma unroll
    for (int ks = 0; ks < 8; ++ks) {
      bf16x8 af[4], bfr[4];
      #pragma unroll
      for (int mt = 0; mt < 4; ++mt)
        af[mt] = __builtin_bit_cast(bf16x8,
                   *(const u16x8*)(&sAx[eh * 64 + mt * 16 + m15][ks * 32 + quad * 8]));
      #pragma unroll
      for (int nt = 0; nt < 4; ++nt)
        bfr[nt] = __builtin_bit_cast(bf16x8,
                   *(const u16x8*)(&sW1T[ch * 64 + nt * 16 + m15][ks * 32 + quad * 8]));
      #pragma unroll
      for (int mt = 0; mt < 4; ++mt)
        #pragma unroll
        for (int nt = 0; nt < 4; ++nt)
          acc[mt][nt] = __builtin_amdgcn_mfma_f32_16x16x32_bf16(af[mt], bfr[nt], acc[mt][nt], 0, 0, 0);
    }

    #pragma unroll
    for (int mt = 0; mt < 4; ++mt) {
      #pragma unroll
      for (int r = 0; r < 4; ++r) {
        float s = 0.f;
        #pragma unroll
        for (int nt = 0; nt < 4; ++nt) {
          int c = ch * 64 + nt * 16 + m15;
          float h = acc[mt][nt][r] + sB1[c];
          h = fmaxf(h, 0.f);
          s = fmaf(h, sW2[c], s);
        }
        s += __shfl_xor(s, 1);
        s += __shfl_xor(s, 2);
        s += __shfl_xor(s, 4);
        s += __shfl_xor(s, 8);
        if (m15 == 0) sRed[ch][eh * 64 + mt * 16 + quad * 4 + r] = s;
      }
    }
    __syncthreads();

    if (tid < TILE_E) {
      int e = ebase + tid;
      if (e < n_edges) {
        float s = sRed[0][tid] + sRed[1][tid] + b2;
        out[e] = 1.f / (1.f + __expf(-s));
      }
    }
  }
}

extern "C" void kernel_launch(void* const* d_in, const int* in_sizes, int n_in,
                              void* d_out, int out_size, void* d_ws, size_t ws_size,
                              hipStream_t stream) {
  const float* inputs = (const float*)d_in[0];
  const int*   x_idx  = (const int*)d_in[1];
  const int*   y_idx  = (const int*)d_in[2];
  const float* W1     = (const float*)d_in[3];
  const float* bias1  = (const float*)d_in[4];
  const float* W2     = (const float*)d_in[5];
  const float* bias2  = (const float*)d_in[6];
  float* out = (float*)d_out;
  const int n_edges = in_sizes[1];
  const int n_nodes = in_sizes[0] / NHID;

  const size_t need = (size_t)n_nodes * 256;   // fp8: 256 B/node
  if (d_ws != nullptr && ws_size >= need) {
    unsigned char* AB8 = (unsigned char*)d_ws;
    // Phase 1: 32-row tiles, 3 tiles/block (r3/r9/r10 config), fp8 store stage
    const int ntiles = (n_nodes + TILE_R - 1) / TILE_R;
    int grid1 = (ntiles + 2) / 3;
    if (grid1 < 1) grid1 = 1;
    hipLaunchKernelGGL(precompute_ab, dim3(grid1), dim3(256), 0, stream,
                       inputs, W1, bias1, AB8, n_nodes);
    // Phase 2: fp8 gathers (8 B/lane), 4-edge unroll, grid 2048
    hipLaunchKernelGGL(edge_eval, dim3(2048), dim3(256), 0, stream,
                       AB8, x_idx, y_idx, W2, bias2, out, n_edges);
  } else {
    hipLaunchKernelGGL(mlp_edge_decoder, dim3(512), dim3(256), 0, stream,
                       inputs, x_idx, y_idx, W1, bias1, W2, bias2, out, n_edges);
  }
}